// Round 7
// baseline (221.094 us; speedup 1.0000x reference)
//
#include <hip/hip_runtime.h>
#include <hip/hip_bf16.h>

// 2-layer GCN encoder: (GCNConv -> BatchNorm1d(train) -> PReLU) x 2
// N=50000, E=800000, D=128. Inputs f32 (probed), edge_index int64 (probed),
// output f32. Internal: GEMM/agg buffers bf16, math f32.
//
// R20: CSR-build parallelism. k_bin was 256 blocks (1/CU, 4 waves) and
// k_degfill 49 blocks (19% of CUs) -- est. ~100us combined, hidden under the
// 43us harness fills. Buckets shrink 1024 -> 256 nodes (196 buckets):
// packed word = (src<<16)|dst (bucket = bits 8..15, node-in-bucket = bits
// 0..7). k_bin -> 800 blocks x 1000 edges (ebuf 4KB, ~12 waves/CU for the
// scattered bin writes); k_degfill -> 196 blocks x 512 thr (8 waves/CU, 77%
// CU fill, 256-wide scan). CAP=4608 = bucket mean 4096 + 8 sigma; 196*4608*4
// = 3612672 B exactly matches the old binned/csr_src slots. tailc (196 int)
// moves to the free gap at +201728. agg (R19) / gemm (R18) / bn untouched.
//
// ws layout (bytes):
//   [0       .. +200000)   dinv f32[NN]
//   [200704  .. +8)        flags: [0]=int64?, [1]=bf16-floats?
//   [201728  .. +784)      tailc int[196] (zeroed by memset; bucket fills)
//   [404800  .. +200000)   rowptr int[NN] (row starts, gapped CSR)
//   [604816  .. +200000)   rowend int[NN]
//   [806400  .. +65536)    stats1p f32[64][256]
//   [871936  .. +65536)    stats2p f32[64][256]
//   [1048576 .. +3.6MB)    csr_src int[196*4608]
//   [4718592 .. +12.8MB)   hbuf  bf16[NN*DD] packed-slot layout (dinv-scaled)
//   [17518592.. +32768)    wp1 bf16[128*128] swizzled
//   [17551360.. +32768)    wp2 bf16[128*128] swizzled
//   [30056448.. +12.8MB)   aggbuf bf16[NN*DD] row-major
//   [42856448.. +3.6MB)    binned uint[196*4608] packed (src<<16)|dst

typedef __hip_bfloat16 bf16;
typedef __attribute__((ext_vector_type(8))) short short8;   // 8 bf16 = 4 VGPR
typedef __attribute__((ext_vector_type(4))) float f32x4;    // MFMA accumulator

#define NN 50000
#define NE 800000
#define DD 128
#define BN_EPS 1e-5f
#define NBIN 800         // k_bin blocks
#define BIN_CHUNK 1000   // NE / NBIN exactly
#define CAP 4608         // per-bucket capacity (mean 4096 + 8 sigma)
#define NBKT 196         // ceil(50000 / 256)

__device__ __forceinline__ float b2f(bf16 v) { return __bfloat162float(v); }
__device__ __forceinline__ float ldf(const void* p, size_t idx, int isbf) {
  return isbf ? b2f(((const bf16*)p)[idx]) : ((const float*)p)[idx];
}
__device__ __forceinline__ int lde(const void* ei, size_t idx, int is64) {
  return is64 ? (int)((const long long*)ei)[idx] : ((const int*)ei)[idx];
}
__device__ __forceinline__ unsigned int f2bs(float v) {
  bf16 b = __float2bfloat16(v);
  return (unsigned int)*reinterpret_cast<unsigned short*>(&b);
}
__device__ __forceinline__ float bslo(unsigned int u) { return __uint_as_float(u << 16); }
__device__ __forceinline__ float bshi(unsigned int u) { return __uint_as_float(u & 0xFFFF0000u); }
__device__ __forceinline__ float s2f(short v) {
  return __uint_as_float(((unsigned int)(unsigned short)v) << 16);
}

// 800 blocks x 256. Per-block dtype self-probe; block 0 publishes flags;
// blocks 0..63 swizzle W1, 64..127 swizzle W2; all bin their 1000-edge chunk
// into packed binned[] at zero-based bucket counters (tailc pre-zeroed).
// Packed word u = (src<<16) | dst; bucket = (u>>8)&0xFF, local = u&0xFF.
__global__ __launch_bounds__(256) void k_bin(const int* ei_i, const unsigned short* x16,
                                             const void* W1, const void* W2,
                                             unsigned short* wp1, unsigned short* wp2,
                                             int* flags, int* tailc, unsigned int* binned) {
  __shared__ int cnt[NBKT], cur[NBKT], gb[NBKT], sflags[2];
  __shared__ unsigned int ebuf[BIN_CHUNK];  // 4 KB
  const int tid = threadIdx.x;
  const int bid = blockIdx.x;
  if (tid < 64) {
    unsigned long long m1 = __ballot(ei_i[2 * tid + 1] != 0);
    int ex = (x16[2 * tid] >> 7) & 0xFF;
    unsigned long long m2 = __ballot(ex >= 90 && ex <= 140);
    if (tid == 0) {
      sflags[0] = (m1 == 0ull) ? 1 : 0;
      sflags[1] = (__popcll(m2) >= 48) ? 1 : 0;
    }
  }
  if (tid < NBKT) { cnt[tid] = 0; cur[tid] = 0; }
  __syncthreads();
  const int is64 = sflags[0], isbf = sflags[1];
  if (bid == 0 && tid == 0) { flags[0] = is64; flags[1] = isbf; }
  if (bid < 128) {  // W swizzle side-job
    const void* W = bid < 64 ? W1 : W2;
    unsigned short* wp = bid < 64 ? wp1 : wp2;
    int idx = (bid & 63) * 256 + tid;
    int k = idx >> 7, n = idx & 127;
    wp[(k >> 3) * 1024 + n * 8 + (k & 7)] = (unsigned short)f2bs(ldf(W, idx, isbf));
  }
  const void* ei = (const void*)ei_i;
  const int e0 = bid * BIN_CHUNK;
  for (int t = tid; t < BIN_CHUNK; t += 256) {
    int s = lde(ei, (size_t)(e0 + t), is64);
    int d = lde(ei, (size_t)NE + e0 + t, is64);
    ebuf[t] = ((unsigned)s << 16) | (unsigned)d;
    atomicAdd(&cnt[d >> 8], 1);
  }
  __syncthreads();
  if (tid < NBKT && cnt[tid] > 0) gb[tid] = tid * CAP + atomicAdd(&tailc[tid], cnt[tid]);
  __syncthreads();
  for (int t = tid; t < BIN_CHUNK; t += 256) {
    unsigned int u = ebuf[t];
    int b = (int)((u >> 8) & 0xFF);
    int r = atomicAdd(&cur[b], 1);
    binned[gb[b] + r] = u;
  }
}

// Per-bucket (256 nodes): degree hist (LDS) -> dinv/rowptr/rowend, then exact
// CSR fill with LDS cursors. 196 blocks x 512 (edge passes use all 512, scan
// uses 256). Packed u: src=u>>16, local=u&0xFF.
__global__ __launch_bounds__(512) void k_degfill(const unsigned int* binned, const int* tailc,
                                                 float* dinv, int* rowptr, int* rowend,
                                                 int* csr_src) {
  __shared__ int hist[256];
  const int b = blockIdx.x;
  const int t = threadIdx.x;
  if (t < 256) hist[t] = 0;
  __syncthreads();
  const int eb = b * CAP, ee = eb + tailc[b];
  for (int e = eb + t; e < ee; e += 512) atomicAdd(&hist[binned[e] & 0xFF], 1);
  __syncthreads();
  int h = 0;
  if (t < 256) h = hist[t];
  __syncthreads();
  for (int off = 1; off < 256; off <<= 1) {  // inclusive scan over 256
    int u = 0;
    if (t < 256 && t >= off) u = hist[t - off];
    __syncthreads();
    if (t < 256) hist[t] += u;
    __syncthreads();
  }
  if (t < 256) {
    int start = eb + hist[t] - h;  // exclusive prefix, global position
    int node = b * 256 + t;
    if (node < NN) {
      rowptr[node] = start;
      rowend[node] = start + h;
      dinv[node] = rsqrtf((float)(h + 1));  // +1 self-loop
    }
    hist[t] = start;  // repurpose as fill cursor
  }
  __syncthreads();
  for (int e = eb + t; e < ee; e += 512) {
    unsigned int u = binned[e];
    int pos = atomicAdd(&hist[u & 0xFF], 1);
    csr_src[pos] = (int)(u >> 16);
  }
}

// MFMA GEMM, 64 rows/block (782 blocks). out = dinv-prescaled bf16 in
// packed-slot layout: row r, u32 slot s holds bf16 pair (col s, col s+64).
// W pre-swizzled (wp), raw LDS copy. XMODE 0: layer-1 input (probe f32/bf16).
// XMODE 2: aggbuf bf16 + fused BN1 (stats from 64-copy partials statsp).
// Blocks 0..63 zero zstats (consumed by the NEXT kernel's atomics --
// stream-ordered, safe).
template <int XMODE>
__global__ __launch_bounds__(256) void k_gemm(const void* in_, const unsigned short* wp,
                                              const int* flags, const float* dinv,
                                              const float* statsp, const void* g,
                                              const void* be, const void* al,
                                              float* zstats, unsigned int* out) {
  __shared__ alignas(16) short sW[16 * 128 * 8];  // 32 KB
  __shared__ float sSc[DD], sSh[DD], sAl;
  const int isbf = flags[1];
  const int tid = threadIdx.x;

  if (blockIdx.x < 64) zstats[blockIdx.x * 256 + tid] = 0.f;
  {
    const short8* src = (const short8*)wp;
    short8* dst = (short8*)sW;
#pragma unroll
    for (int i = 0; i < 8; i++) dst[tid + i * 256] = src[tid + i * 256];
  }
  if (XMODE == 2) {
    if (tid < DD) {
      float s = 0.f, q = 0.f;
#pragma unroll 8
      for (int k = 0; k < 64; k++) {
        s += statsp[k * 256 + tid];
        q += statsp[k * 256 + 128 + tid];
      }
      const float inv_n = 1.0f / NN;
      float mu = s * inv_n;
      float var = q * inv_n - mu * mu;
      float sc = rsqrtf(var + BN_EPS) * ldf(g, tid, isbf);
      sSc[tid] = sc;
      sSh[tid] = ldf(be, tid, isbf) - mu * sc;
    }
    if (tid == 0) sAl = ldf(al, 0, isbf);
  }
  __syncthreads();

  const int wave = tid >> 6;
  const int lane = tid & 63;
  const int quad = lane >> 4;
  const int m16 = lane & 15;
  const int r0 = blockIdx.x * 64 + wave * 16;

  f32x4 acc[8];
#pragma unroll
  for (int n = 0; n < 8; n++) acc[n] = (f32x4){0.f, 0.f, 0.f, 0.f};

#pragma unroll
  for (int q = 0; q < 4; q++) {
    const int kq = q * 32 + quad * 8;
    short8 af;
    {
      int row = r0 + m16;
      row = row < NN ? row : NN - 1;  // clamp; garbage rows never stored
      if (XMODE == 2) {
        short8 raw = *(const short8*)((const short*)in_ + (size_t)row * DD + kq);
        short8 f;
#pragma unroll
        for (int jj = 0; jj < 8; jj++) {
          float y = s2f(raw[jj]);
          y = y * sSc[kq + jj] + sSh[kq + jj];
          y = y > 0.f ? y : sAl * y;
          f[jj] = (short)f2bs(y);
        }
        af = f;
      } else if (isbf) {
        af = *(const short8*)((const short*)in_ + (size_t)row * DD + kq);
      } else {
        const float* ap = (const float*)in_ + (size_t)row * DD + kq;
        const float4 u0 = *(const float4*)ap;
        const float4 u1 = *(const float4*)(ap + 4);
        float v[8] = {u0.x, u0.y, u0.z, u0.w, u1.x, u1.y, u1.z, u1.w};
        short8 f;
#pragma unroll
        for (int jj = 0; jj < 8; jj++) f[jj] = (short)f2bs(v[jj]);
        af = f;
      }
    }
    const int c = q * 4 + quad;
    const short* bp = sW + c * 1024 + m16 * 8;
#pragma unroll
    for (int n = 0; n < 8; n++) {
      const short8 bfrag = *(const short8*)(bp + n * 128);
      acc[n] = __builtin_amdgcn_mfma_f32_16x16x32_bf16(af, bfrag, acc[n], 0, 0, 0);
    }
  }

#pragma unroll
  for (int r = 0; r < 4; r++) {
    int row = r0 + quad * 4 + r;
    if (row < NN) {
      float di = dinv[row];
      unsigned int* orow = out + (size_t)row * 64;
#pragma unroll
      for (int n = 0; n < 4; n++) {
        unsigned int p = (f2bs(di * acc[n + 4][r]) << 16) | f2bs(di * acc[n][r]);
        orow[n * 16 + m16] = p;
      }
    }
  }
}

// One wave per node (12500 blocks = 50000 waves exactly). Row range
// [rowptr[w], rowend[w]) in the gapped CSR via readfirstlane -> scalar pipe.
// Main loop: 16-deep gather window. Remainder r in [1,16): ONE predicated
// 16-deep batch (index clamp e+(k<r?k:0); dup addrs = cache hits; masked
// branch-free accumulate) instead of serial 4-deep/1-deep tails.
__global__ __launch_bounds__(256) void k_agg(const unsigned int* hs, const float* dinv,
                                             const int* rowptr, const int* rowend,
                                             const int* csr_src, const void* bias,
                                             const int* flags, unsigned short* out,
                                             float* statsp) {
  const int tid = threadIdx.x;
  const int w = (blockIdx.x * 256 + tid) >> 6;   // never >= NN (12500*4 == NN)
  const int lane = tid & 63;
  const float dd_ = dinv[w];
  unsigned int hv = hs[(size_t)w * 64 + lane];
  float ax = bslo(hv), ay = bshi(hv);
  int e = __builtin_amdgcn_readfirstlane(rowptr[w]);
  const int e1 = __builtin_amdgcn_readfirstlane(rowend[w]);

  for (; e + 16 <= e1; e += 16) {
    int s[16];
#pragma unroll
    for (int k = 0; k < 16; k++) s[k] = csr_src[e + k];
    unsigned int v[16];
#pragma unroll
    for (int k = 0; k < 16; k++) v[k] = hs[(size_t)s[k] * 64 + lane];
#pragma unroll
    for (int k = 0; k < 16; k++) { ax += bslo(v[k]); ay += bshi(v[k]); }
  }
  const int r = e1 - e;  // 0..15, wave-uniform
  if (r > 0) {
    int s[16];
#pragma unroll
    for (int k = 0; k < 16; k++) s[k] = csr_src[e + (k < r ? k : 0)];
    unsigned int v[16];
#pragma unroll
    for (int k = 0; k < 16; k++) v[k] = hs[(size_t)s[k] * 64 + lane];
#pragma unroll
    for (int k = 0; k < 16; k++) {
      const float m = (k < r) ? 1.f : 0.f;
      ax += m * bslo(v[k]);
      ay += m * bshi(v[k]);
    }
  }

  int isbf = flags[1];
  float o1 = dd_ * ax + ldf(bias, lane, isbf);
  float o2 = dd_ * ay + ldf(bias, lane + 64, isbf);
  unsigned short* orow = out + (size_t)w * DD;
  orow[lane] = (unsigned short)f2bs(o1);
  orow[lane + 64] = (unsigned short)f2bs(o2);

  __shared__ float rs1[256], rq1[256], rs2[256], rq2[256];
  rs1[tid] = o1; rq1[tid] = o1 * o1;
  rs2[tid] = o2; rq2[tid] = o2 * o2;
  __syncthreads();
  float* p = statsp + (blockIdx.x & 63) * 256;
  if (tid < 64) {  // col tid
    float s = rs1[tid] + rs1[tid + 64] + rs1[tid + 128] + rs1[tid + 192];
    float q = rq1[tid] + rq1[tid + 64] + rq1[tid + 128] + rq1[tid + 192];
    atomicAdd(&p[tid], s);
    atomicAdd(&p[128 + tid], q);
  } else if (tid < 128) {  // col tid (= 64 + lane)
    int l = tid - 64;
    float s = rs2[l] + rs2[l + 64] + rs2[l + 128] + rs2[l + 192];
    float q = rq2[l] + rq2[l + 64] + rq2[l + 128] + rq2[l + 192];
    atomicAdd(&p[tid], s);
    atomicAdd(&p[128 + tid], q);
  }
}

// Final BN+PReLU: 1024 grid-stride blocks. Prologue sums the 64 stat copies
// into LDS sc/sh (one rsqrt per column per block, not per element).
__global__ __launch_bounds__(256) void k_bn_apply(const unsigned int* x32, const float* statsp,
                                                  const void* g, const void* be, const void* al,
                                                  const int* flags, void* out) {
  __shared__ float sSc[DD], sSh[DD], sAl;
  const int tid = threadIdx.x;
  const int isbf = flags[1];
  if (tid < DD) {
    float s = 0.f, q = 0.f;
#pragma unroll 8
    for (int k = 0; k < 64; k++) {
      s += statsp[k * 256 + tid];
      q += statsp[k * 256 + 128 + tid];
    }
    const float inv_n = 1.0f / NN;
    float mu = s * inv_n;
    float var = q * inv_n - mu * mu;
    float sc = rsqrtf(var + BN_EPS) * ldf(g, tid, isbf);
    sSc[tid] = sc;
    sSh[tid] = ldf(be, tid, isbf) - mu * sc;
  }
  if (tid == 0) sAl = ldf(al, 0, isbf);
  __syncthreads();
  const float alpha = sAl;
  for (int i4 = blockIdx.x * 256 + tid; i4 < NN * 32; i4 += gridDim.x * 256) {
    int jq = (i4 & 31) * 4;
    const uint2 xv = ((const uint2*)x32)[i4];
    float xa[4] = {bslo(xv.x), bshi(xv.x), bslo(xv.y), bshi(xv.y)};
    float y[4];
#pragma unroll
    for (int u = 0; u < 4; u++) {
      int j = jq + u;
      float v = xa[u] * sSc[j] + sSh[j];
      y[u] = v > 0.f ? v : alpha * v;
    }
    if (isbf) {
      uint2 o;
      o.x = (f2bs(y[1]) << 16) | f2bs(y[0]);
      o.y = (f2bs(y[3]) << 16) | f2bs(y[2]);
      ((uint2*)out)[i4] = o;
    } else {
      float4 o = {y[0], y[1], y[2], y[3]};
      ((float4*)out)[i4] = o;
    }
  }
}

extern "C" void kernel_launch(void* const* d_in, const int* in_sizes, int n_in,
                              void* d_out, int out_size, void* d_ws, size_t ws_size,
                              hipStream_t stream) {
  const void* x = d_in[0];
  const int* ei = (const int*)d_in[1];
  const void* W1 = d_in[2];
  const void* b1 = d_in[3];
  const void* g1 = d_in[4];
  const void* be1 = d_in[5];
  const void* a1 = d_in[6];
  const void* W2 = d_in[7];
  const void* b2 = d_in[8];
  const void* g2 = d_in[9];
  const void* be2 = d_in[10];
  const void* a2 = d_in[11];

  char* w = (char*)d_ws;
  float* dinv = (float*)w;                              // 200000
  int* flags = (int*)(w + 200704);                      // 8
  int* tailc = (int*)(w + 201728);                      // 784 (196 int)
  int* rowptr = (int*)(w + 404800);                     // 200000
  int* rowend = (int*)(w + 604816);                     // 200000
  float* stats1p = (float*)(w + 806400);                // 65536
  float* stats2p = (float*)(w + 871936);                // 65536
  int* csr_src = (int*)(w + 1048576);                   // 3612672
  unsigned int* hbuf = (unsigned int*)(w + 4718592);    // 12800000
  unsigned short* wp1 = (unsigned short*)(w + 17518592);   // 32768
  unsigned short* wp2 = (unsigned short*)(w + 17551360);   // 32768
  unsigned short* aggbuf = (unsigned short*)(w + 30056448);  // 12800000
  unsigned int* binned = (unsigned int*)(w + 42856448);  // 3612672

  const int NB_G = (NN + 63) / 64;     // 782
  const int NB_W = NN * 64 / 256;      // 12500

  hipMemsetAsync(tailc, 0, 784, stream);
  k_bin<<<dim3(NBIN), dim3(256), 0, stream>>>(ei, (const unsigned short*)x, W1, W2,
                                              wp1, wp2, flags, tailc, binned);
  k_degfill<<<dim3(NBKT), dim3(512), 0, stream>>>(binned, tailc, dinv, rowptr, rowend,
                                                  csr_src);

  // ---- layer 1 ----
  k_gemm<0><<<dim3(NB_G), dim3(256), 0, stream>>>(x, wp1, flags, dinv,
                                                  nullptr, nullptr, nullptr, nullptr,
                                                  stats1p, hbuf);
  k_agg<<<dim3(NB_W), dim3(256), 0, stream>>>(hbuf, dinv, rowptr, rowend, csr_src,
                                              b1, flags, aggbuf, stats1p);

  // ---- layer 2 (BN1+PReLU fused into GEMM A-path via stats1p) ----
  k_gemm<2><<<dim3(NB_G), dim3(256), 0, stream>>>(aggbuf, wp2, flags, dinv,
                                                  stats1p, g1, be1, a1, stats2p, hbuf);
  k_agg<<<dim3(NB_W), dim3(256), 0, stream>>>(hbuf, dinv, rowptr, rowend, csr_src,
                                              b2, flags, aggbuf, stats2p);
  k_bn_apply<<<dim3(1024), dim3(256), 0, stream>>>((const unsigned int*)aggbuf, stats2p,
                                                   g2, be2, a2, flags, d_out);
}